// Round 8
// baseline (152.231 us; speedup 1.0000x reference)
//
#include <hip/hip_runtime.h>

#define MAX_REL 16
#define NTAB    33          // 2*MAX_REL+1
#define B       4
#define H       8
#define LQ      1024
#define DH      64
#define KLEN    1024
#define QTILE   16          // q rows per block (4 per wave)
#define PRS     48          // pr row stride (floats)

typedef short s16x8 __attribute__((ext_vector_type(8)));   // 8 bf16 (4 VGPRs)
typedef float f32x4 __attribute__((ext_vector_type(4)));   // native float4

// round-to-nearest-even f32 -> bf16
static __device__ __forceinline__ short f2bf(float f) {
    unsigned u = __float_as_uint(f);
    unsigned r = (u + 0x7FFFu + ((u >> 16) & 1u)) >> 16;
    return (short)r;
}

// One block = (b, h, 16 q-rows); 4 waves.
// Phase 1: stage Q and T as bf16 MFMA fragments in LDS; ONE barrier.
//   (ts is NOT staged: tk comes from direct global int4 loads (L1-hot, 4 KB/b),
//    tq from a wave-uniform scalar load.)
// Phase 2 (wave-private, barrier-free): full 16x48 proj tile via 6 MFMAs
//   (duplicated per wave; MFMA pipe idle); lanes quad==wave own rows 4w..4w+3
//   (D layout: row = quad*4+reg, col = lane&15) and write them to pr.
// Phase 3 (wave-private): sorted time_ids => per (row, 256-k chunk) idx is
//   almost always saturated (0 or 32). Wave-uniform __all test skips the LDS
//   gather for saturated chunks (2-value select); nontemporal f32x4 stores.
__global__ __launch_bounds__(256) void fused_pe_kernel(const float* __restrict__ query,
                                                       const float* __restrict__ table,
                                                       const int* __restrict__ time_ids,
                                                       float* __restrict__ out) {
    __shared__ short qth[2 * 64 * 8];        // A-frags [kstep][lane][j]    2 KB
    __shared__ short tbh[2 * 4 * 48 * 8];    // B-frags [kstep][quad][n][j] 6 KB
    __shared__ float pr[QTILE * PRS];        // 3 KB

    const int tid  = threadIdx.x;
    const int wave = tid >> 6;
    const int lane = tid & 63;
    const int tile = blockIdx.x;             // 0 .. B*H*64-1
    const int bh   = tile >> 6;
    const int qt_i = tile & 63;
    const int b    = bh >> 3;                // H = 8
    const int q0   = qt_i * QTILE;
    const int rowbase = bh * LQ + q0;
    const int* tsb = time_ids + b * KLEN;

    // ---- Phase 1: fragment staging (bf16) ----
    {   // Q tile: float4 index tid covers element (m, 4c..4c+3)
        float4 v = ((const float4*)(query + (size_t)rowbase * DH))[tid];
        int m = tid >> 4, c = tid & 15;
        int kstep = c >> 3, quad = (c >> 1) & 3, jb = (c & 1) << 2;
        short4 hv = make_short4(f2bf(v.x), f2bf(v.y), f2bf(v.z), f2bf(v.w));
        *(short4*)(qth + ((kstep * 64 + quad * 16 + m) << 3) + jb) = hv;
    }
    for (int i = tid; i < NTAB * 16; i += 256) {   // table rows 0..32
        int n = i >> 4, c = i & 15;
        float4 v = ((const float4*)table)[i];
        int kstep = c >> 3, quad = (c >> 1) & 3, jb = (c & 1) << 2;
        short4 hv = make_short4(f2bf(v.x), f2bf(v.y), f2bf(v.z), f2bf(v.w));
        *(short4*)(tbh + (((kstep * 4 + quad) * 48 + n) << 3) + jb) = hv;
    }
    // tk: direct global loads (overlap with staging latency)
    const int4 tk0 = ((const int4*)tsb)[0 * 64 + lane];
    const int4 tk1 = ((const int4*)tsb)[1 * 64 + lane];
    const int4 tk2 = ((const int4*)tsb)[2 * 64 + lane];
    const int4 tk3 = ((const int4*)tsb)[3 * 64 + lane];
    __syncthreads();                         // the only barrier

    // ---- Phase 2: MFMA proj, wave-private writes ----
    const int quad = lane >> 4;
    const int nlo  = lane & 15;
    f32x4 acc0 = {0.f, 0.f, 0.f, 0.f}, acc1 = acc0, acc2 = acc0;
#pragma unroll
    for (int kstep = 0; kstep < 2; ++kstep) {
        s16x8 a = *(const s16x8*)(qth + ((kstep * 64 + lane) << 3));
        const short* bbase = tbh + (((kstep * 4 + quad) * 48) << 3);
        s16x8 b0 = *(const s16x8*)(bbase + (nlo << 3));
        s16x8 b1 = *(const s16x8*)(bbase + ((nlo + 16) << 3));
        s16x8 b2 = *(const s16x8*)(bbase + (32 << 3));   // n=32 broadcast
        acc0 = __builtin_amdgcn_mfma_f32_16x16x32_bf16(a, b0, acc0, 0, 0, 0);
        acc1 = __builtin_amdgcn_mfma_f32_16x16x32_bf16(a, b1, acc1, 0, 0, 0);
        acc2 = __builtin_amdgcn_mfma_f32_16x16x32_bf16(a, b2, acc2, 0, 0, 0);
    }
    if (quad == wave) {                      // lanes holding rows 4w..4w+3
#pragma unroll
        for (int i = 0; i < 4; ++i) {
            int row = wave * 4 + i;
            pr[row * PRS + nlo]      = acc0[i];
            pr[row * PRS + 16 + nlo] = acc1[i];
            pr[row * PRS + 32]       = acc2[i];
        }
    }
    // no barrier: pr rows 4w..4w+3 written and read by wave w only

    // ---- Phase 3: saturation-aware gather + nontemporal stores ----
#pragma unroll
    for (int r = 0; r < 4; ++r) {
        const int row = wave * 4 + r;
        const int tq  = tsb[q0 + row];       // wave-uniform -> scalar load
        const float* prr = pr + row * PRS;
        const float p0  = prr[0];            // LDS broadcast
        const float p32 = prr[32];           // LDS broadcast
        float* op = out + (size_t)(rowbase + row) * KLEN + (lane << 2);
#pragma unroll
        for (int c = 0; c < 4; ++c) {
            int4 tk = (c == 0) ? tk0 : (c == 1) ? tk1 : (c == 2) ? tk2 : tk3;
            // lane fully below window (tk sorted: .w is max) or fully above (.x is min)
            bool flo = (tk.w - tq) <= -MAX_REL;
            bool fhi = (tk.x - tq) >=  MAX_REL;
            f32x4 v;
            if (__all(flo | fhi)) {          // wave-uniform fast path (~13/16 chunks)
                float s = flo ? p0 : p32;
                v = (f32x4){s, s, s, s};
            } else {
                int i0 = min(max(tk.x - tq, -MAX_REL), MAX_REL) + MAX_REL;
                int i1 = min(max(tk.y - tq, -MAX_REL), MAX_REL) + MAX_REL;
                int i2 = min(max(tk.z - tq, -MAX_REL), MAX_REL) + MAX_REL;
                int i3 = min(max(tk.w - tq, -MAX_REL), MAX_REL) + MAX_REL;
                v = (f32x4){prr[i0], prr[i1], prr[i2], prr[i3]};
            }
            __builtin_nontemporal_store(v, (f32x4*)(op + c * 256));
        }
    }
}

extern "C" void kernel_launch(void* const* d_in, const int* in_sizes, int n_in,
                              void* d_out, int out_size, void* d_ws, size_t ws_size,
                              hipStream_t stream) {
    const float* query    = (const float*)d_in[0];   // (B,H,LQ,DH) f32
    const float* table    = (const float*)d_in[1];   // (33, DH) f32
    const int*   time_ids = (const int*)d_in[2];     // (B, KLEN) int32
    float* out = (float*)d_out;                      // (B,H,LQ,KLEN) f32

    fused_pe_kernel<<<B * H * (LQ / QTILE), 256, 0, stream>>>(query, table, time_ids, out);
}

// Round 9
// 143.767 us; speedup vs baseline: 1.0589x; 1.0589x over previous
//
#include <hip/hip_runtime.h>

#define MAX_REL 16
#define NTAB    33          // 2*MAX_REL+1
#define B       4
#define H       8
#define LQ      1024
#define DH      64
#define KLEN    1024
#define QTILE   16          // q rows per block (4 per wave)
#define PRS     48          // pr row stride (floats)

typedef short s16x8 __attribute__((ext_vector_type(8)));   // 8 bf16 (4 VGPRs)
typedef float f32x4 __attribute__((ext_vector_type(4)));   // MFMA acc

// round-to-nearest-even f32 -> bf16
static __device__ __forceinline__ short f2bf(float f) {
    unsigned u = __float_as_uint(f);
    unsigned r = (u + 0x7FFFu + ((u >> 16) & 1u)) >> 16;
    return (short)r;
}

// One block = (b, h, 16 q-rows); 4 waves. (R6 structure + saturation fast path)
// Phase 1: stage ts (int), Q and T as bf16 MFMA fragments; ONE barrier.
// Phase 2 (wave-private, barrier-free): full 16x48 proj tile via 6 MFMAs
//   (duplicated per wave; MFMA pipe idle); lanes quad==wave own rows 4w..4w+3
//   (D layout: row = quad*4+reg, col = lane&15) and write them to pr.
// Phase 3 (wave-private): sorted time_ids => per (row, 256-k chunk) idx is
//   almost always saturated (0 or 32). Wave-uniform __all test replaces the
//   16-read LDS gather with 2 broadcast reads + select for ~13/16 chunks.
__global__ __launch_bounds__(256) void fused_pe_kernel(const float* __restrict__ query,
                                                       const float* __restrict__ table,
                                                       const int* __restrict__ time_ids,
                                                       float* __restrict__ out) {
    __shared__ int   ts[KLEN];               // 4 KB
    __shared__ short qth[2 * 64 * 8];        // A-frags [kstep][lane][j]    2 KB
    __shared__ short tbh[2 * 4 * 48 * 8];    // B-frags [kstep][quad][n][j] 6 KB
    __shared__ float pr[QTILE * PRS];        // 3 KB

    const int tid  = threadIdx.x;
    const int wave = tid >> 6;
    const int lane = tid & 63;
    const int tile = blockIdx.x;             // 0 .. B*H*64-1
    const int bh   = tile >> 6;
    const int qt_i = tile & 63;
    const int b    = bh >> 3;                // H = 8
    const int q0   = qt_i * QTILE;
    const int rowbase = bh * LQ + q0;

    // ---- Phase 1: staging ----
    ((int4*)ts)[tid] = ((const int4*)(time_ids + b * KLEN))[tid];
    {   // Q tile: float4 index tid covers element (m, 4c..4c+3)
        float4 v = ((const float4*)(query + (size_t)rowbase * DH))[tid];
        int m = tid >> 4, c = tid & 15;
        int kstep = c >> 3, quad = (c >> 1) & 3, jb = (c & 1) << 2;
        short4 hv = make_short4(f2bf(v.x), f2bf(v.y), f2bf(v.z), f2bf(v.w));
        *(short4*)(qth + ((kstep * 64 + quad * 16 + m) << 3) + jb) = hv;
    }
    for (int i = tid; i < NTAB * 16; i += 256) {   // table rows 0..32
        int n = i >> 4, c = i & 15;
        float4 v = ((const float4*)table)[i];
        int kstep = c >> 3, quad = (c >> 1) & 3, jb = (c & 1) << 2;
        short4 hv = make_short4(f2bf(v.x), f2bf(v.y), f2bf(v.z), f2bf(v.w));
        *(short4*)(tbh + (((kstep * 4 + quad) * 48 + n) << 3) + jb) = hv;
    }
    __syncthreads();                         // the only barrier

    // ---- Phase 2: MFMA proj, wave-private writes ----
    const int quad = lane >> 4;
    const int nlo  = lane & 15;
    f32x4 acc0 = {0.f, 0.f, 0.f, 0.f}, acc1 = acc0, acc2 = acc0;
#pragma unroll
    for (int kstep = 0; kstep < 2; ++kstep) {
        s16x8 a = *(const s16x8*)(qth + ((kstep * 64 + lane) << 3));
        const short* bbase = tbh + (((kstep * 4 + quad) * 48) << 3);
        s16x8 b0 = *(const s16x8*)(bbase + (nlo << 3));
        s16x8 b1 = *(const s16x8*)(bbase + ((nlo + 16) << 3));
        s16x8 b2 = *(const s16x8*)(bbase + (32 << 3));   // n=32 broadcast
        acc0 = __builtin_amdgcn_mfma_f32_16x16x32_bf16(a, b0, acc0, 0, 0, 0);
        acc1 = __builtin_amdgcn_mfma_f32_16x16x32_bf16(a, b1, acc1, 0, 0, 0);
        acc2 = __builtin_amdgcn_mfma_f32_16x16x32_bf16(a, b2, acc2, 0, 0, 0);
    }
    if (quad == wave) {                      // lanes holding rows 4w..4w+3
#pragma unroll
        for (int i = 0; i < 4; ++i) {
            int row = wave * 4 + i;
            pr[row * PRS + nlo]      = acc0[i];
            pr[row * PRS + 16 + nlo] = acc1[i];
            pr[row * PRS + 32]       = acc2[i];
        }
    }
    // no barrier: pr rows 4w..4w+3 written and read by wave w only

    // ---- Phase 3: saturation-aware gather + coalesced float4 stores ----
    const int4 tk0 = ((const int4*)ts)[0 * 64 + lane];
    const int4 tk1 = ((const int4*)ts)[1 * 64 + lane];
    const int4 tk2 = ((const int4*)ts)[2 * 64 + lane];
    const int4 tk3 = ((const int4*)ts)[3 * 64 + lane];

#pragma unroll
    for (int r = 0; r < 4; ++r) {
        const int row = wave * 4 + r;
        const int tq  = ts[q0 + row];        // LDS broadcast (wave-uniform)
        const float* prr = pr + row * PRS;
        const float p0  = prr[0];            // LDS broadcast
        const float p32 = prr[32];           // LDS broadcast
        float* op = out + (size_t)(rowbase + row) * KLEN + (lane << 2);
#pragma unroll
        for (int c = 0; c < 4; ++c) {
            int4 tk = (c == 0) ? tk0 : (c == 1) ? tk1 : (c == 2) ? tk2 : tk3;
            // lane fully below window (tk sorted: .w is max) or fully above (.x is min)
            bool flo = (tk.w - tq) <= -MAX_REL;
            bool fhi = (tk.x - tq) >=  MAX_REL;
            float4 v;
            if (__all(flo | fhi)) {          // wave-uniform fast path (~13/16 chunks)
                float s = flo ? p0 : p32;
                v = make_float4(s, s, s, s);
            } else {
                int i0 = min(max(tk.x - tq, -MAX_REL), MAX_REL) + MAX_REL;
                int i1 = min(max(tk.y - tq, -MAX_REL), MAX_REL) + MAX_REL;
                int i2 = min(max(tk.z - tq, -MAX_REL), MAX_REL) + MAX_REL;
                int i3 = min(max(tk.w - tq, -MAX_REL), MAX_REL) + MAX_REL;
                v = make_float4(prr[i0], prr[i1], prr[i2], prr[i3]);
            }
            *((float4*)(op + c * 256)) = v;
        }
    }
}

extern "C" void kernel_launch(void* const* d_in, const int* in_sizes, int n_in,
                              void* d_out, int out_size, void* d_ws, size_t ws_size,
                              hipStream_t stream) {
    const float* query    = (const float*)d_in[0];   // (B,H,LQ,DH) f32
    const float* table    = (const float*)d_in[1];   // (33, DH) f32
    const int*   time_ids = (const int*)d_in[2];     // (B, KLEN) int32
    float* out = (float*)d_out;                      // (B,H,LQ,KLEN) f32

    fused_pe_kernel<<<B * H * (LQ / QTILE), 256, 0, stream>>>(query, table, time_ids, out);
}